// Round 8
// baseline (45667.273 us; speedup 1.0000x reference)
//
#include <hip/hip_runtime.h>
#include <math.h>
#include <utility>

#define TB 1024   // batch
#define HH 100    // hidden
#define GG 300    // 3*H gate rows

// ---------------------------------------------------------------------------
// NUMERICS ARE FROZEN — DO NOT TOUCH.
// Only the ocml expf/tanhf profile lands on the reference side of a
// knife-edge decoder argmax logit near-tie. The per-element expression DAG
// (values, pairing, order: acc starts at bias, ascending k, 4-term groups
// w0*x0+w1*x1+w2*x2+w3*x3) must stay bit-identical. The gemm+rec split was
// VERIFIED in R16/R17 (passed, absmax 0.0039).
//
// RESIDENCY LAW (R10-R17, 8 data points): the ONLY proven no-scratch recipe
// for large per-thread arrays is R10's: launch_bounds(640,3) (cap 84),
// thread-per-row, wih[<=100] one-time load + IN-LOOP pinN (AGPR-resident,
// VALU reads AGPR directly, FETCH flat), small (~10-40) arch-live working
// set. Both 320-thread gemm variants (R16 SS=16, R17 SS=12) spilled to
// scratch (FETCH 4.5-4.9GB, VGPR=128) — novel-structure register gambles
// keep losing. R18: gemm_gi rewritten in the R10-EXACT pattern:
// 640 thr = 2 teams x 320 rows, wih in regs+pins, x_s[2][10][KP] broadcast,
// acc[10], grid 512 (2 blocks/CU so barriers overlap). gru_rec unchanged.
// ---------------------------------------------------------------------------
__device__ __forceinline__ float sigmoidf_(float x) {
    return 1.0f / (1.0f + expf(-x));
}
__device__ __forceinline__ float tanhf_(float x) {
    return tanhf(x);
}

template<size_t... Is>
__device__ __forceinline__ void ldN(std::index_sequence<Is...>,
                                    float* __restrict__ dst,
                                    const float* __restrict__ src) {
    ((dst[Is] = src[Is]), ...);
}
__device__ __forceinline__ float pin_val(float v) {
    asm volatile("" : "+v"(v));
    return v;
}
template<size_t... Is>
__device__ __forceinline__ void pinN(std::index_sequence<Is...>, float* w) {
    ((w[Is] = pin_val(w[Is])), ...);
}

// ======================= R15/R16-verified 3-gate helpers ====================
template<int GGi, int BT, int LD, int NREG>
__device__ __forceinline__ void grp_reg(const float (&w)[3][NREG],
                                        const float (*vec)[LD], int e0,
                                        float (&acc)[3][BT]) {
    float4 vv[BT];
    #pragma unroll
    for (int b = 0; b < BT; ++b)
        vv[b] = *reinterpret_cast<const float4*>(&vec[e0 + b][GGi * 4]);
    #pragma unroll
    for (int g3 = 0; g3 < 3; ++g3) {
        #pragma unroll
        for (int b = 0; b < BT; ++b)
            acc[g3][b] += w[g3][GGi * 4]     * vv[b].x + w[g3][GGi * 4 + 1] * vv[b].y
                        + w[g3][GGi * 4 + 2] * vv[b].z + w[g3][GGi * 4 + 3] * vv[b].w;
    }
}
template<int BT, int LD, int NREG, size_t... Is>
__device__ __forceinline__ void dot_reg(std::index_sequence<Is...>,
                                        const float (&w)[3][NREG],
                                        const float (*vec)[LD], int e0,
                                        float (&acc)[3][BT]) {
    (grp_reg<(int)Is, BT, LD, NREG>(w, vec, e0, acc), ...);
}

template<int GGi, int OFF, int BT, int LD, int NG>
__device__ __forceinline__ void grp_lds3(const float (&wl)[3][NG][HH][4],
                                         int ii,
                                         const float (*vec)[LD], int e0,
                                         float (&acc)[3][BT]) {
    float4 vv[BT];
    #pragma unroll
    for (int b = 0; b < BT; ++b)
        vv[b] = *reinterpret_cast<const float4*>(&vec[e0 + b][GGi * 4]);
    #pragma unroll
    for (int g3 = 0; g3 < 3; ++g3) {
        const float4 wv = *reinterpret_cast<const float4*>(wl[g3][GGi - OFF][ii]);
        #pragma unroll
        for (int b = 0; b < BT; ++b)
            acc[g3][b] += wv.x * vv[b].x + wv.y * vv[b].y
                        + wv.z * vv[b].z + wv.w * vv[b].w;
    }
}
template<int OFF, int BT, int LD, int NG, size_t... Is>
__device__ __forceinline__ void dot_lds3(std::index_sequence<Is...>,
                                         const float (&wl)[3][NG][HH][4],
                                         int ii,
                                         const float (*vec)[LD], int e0,
                                         float (&acc)[3][BT]) {
    (grp_lds3<(int)Is + OFF, OFF, BT, LD, NG>(wl, ii, vec, e0, acc), ...);
}

// ===========================================================================
// gemm_gi (R18): gi[n, j] = bih[j] + sum_k Wih[j,k]*x[n,k].
// R10-exact residency: 640 thr = 2 teams x 320 rows (300 + 20 pad clamped);
// wih[KP] per-thread regs + in-loop pins (AGPR, proven); x broadcast from
// LDS; acc[SS=10] arch regs. grid 512 = 2 blocks/CU. Frozen expression:
// acc = bi, then ascending 4-term k-groups (gru_old acc_i DAG, bit-proven).
// ===========================================================================
template<int K>
__global__ __launch_bounds__(640, 3)
void gemm_gi(const float* __restrict__ xin,  // [N, K]
             const float* __restrict__ Wih,  // [300, K]
             const float* __restrict__ bih,  // [300]
             float* __restrict__ gi,         // [N, 300]
             int N)
{
    constexpr int KP = (K + 3) & ~3;   // 28 or 100
    constexpr int NG = KP / 4;
    constexpr int SS = 10;             // slots per team per iteration

    const int tid  = threadIdx.x;
    const int team = tid / 320;
    const int tj   = tid % 320;
    const int jj   = (tj < GG) ? tj : 0;

    __shared__ __align__(16) float x_s[2][SS][KP];   // 8 KB (K=100)

    float wih[KP];
    ldN(std::make_index_sequence<K>{}, wih, Wih + (long)jj * K);
    #pragma unroll
    for (int k = K; k < KP; ++k) wih[k] = 0.f;
    float bi = bih[jj];

    const long step = (long)gridDim.x * (2 * SS);
    for (long base = (long)blockIdx.x * (2 * SS); base < N; base += step) {
        // ---- stage 2*SS slots of x (zero-padded k>=K) ----
        for (int idx = tid; idx < 2 * SS * KP; idx += 640) {
            int  s  = idx / KP, k = idx % KP;
            long sl = base + s;
            (&x_s[0][0][0])[idx] = (k < K && sl < N) ? xin[sl * K + k] : 0.f;
        }
        __syncthreads();

        // in-loop pin: wih stays AGPR/VGPR-resident (R10-proven, zero inst)
        pinN(std::make_index_sequence<KP>{}, wih);
        bi = pin_val(bi);

        float acc[SS];
        #pragma unroll
        for (int s = 0; s < SS; ++s) acc[s] = bi;
        #pragma unroll
        for (int gg = 0; gg < NG; ++gg) {
            #pragma unroll
            for (int s = 0; s < SS; ++s) {
                const float4 xv =
                    *reinterpret_cast<const float4*>(&x_s[team][s][gg * 4]);
                acc[s] += wih[gg * 4]     * xv.x + wih[gg * 4 + 1] * xv.y
                        + wih[gg * 4 + 2] * xv.z + wih[gg * 4 + 3] * xv.w;
            }
        }
        if (tj < GG) {
            #pragma unroll
            for (int s = 0; s < SS; ++s) {
                long sl = base + (long)team * SS + s;
                if (sl < N) gi[sl * 300 + tj] = acc[s];
            }
        }
        __syncthreads();   // x_s reuse guard
    }
}

// ===========================================================================
// gru_rec: h-recurrence only (gi precomputed). Block 256 = 2 teams x 128;
// thread owns gate-rows {ii,100+ii,200+ii}; BT=2 elems/team, NE=4/block,
// grid 256. whh: k<36 in regs (108 floats, safe) + k>=36 in LDS (76.8KB).
// One barrier/step; h double-buffered. VERIFIED in R16/R17.
// ===========================================================================
template<bool EMB, bool WRITE_SEQ>
__global__ __launch_bounds__(256)
void gru_rec(const float* __restrict__ gi,    // [t1-t0, B, 300] (if !EMB)
             const int*   __restrict__ tgt,   // [Tfull, B]      (if EMB)
             const float* __restrict__ table, // [64, 300]       (if EMB)
             const float* __restrict__ Whh,   // [300,100]
             const float* __restrict__ bhh,   // [300]
             const float* __restrict__ h_init,// [B,100] or null -> zeros
             float* __restrict__ seq_out,     // [Tfull,B,100] (if WRITE_SEQ)
             float* __restrict__ h_last,      // [B,100] or null
             int t0, int t1)
{
    constexpr int HREG = 36;
    constexpr int GHR  = HREG / 4;       // 9
    constexpr int GHL  = HH / 4 - GHR;   // 16
    constexpr int BT   = 2;
    constexpr int NE   = 4;

    const int tid  = threadIdx.x;
    const int team = tid >> 7;
    const int li   = tid & 127;
    const bool act = (li < HH);
    const int ii   = act ? li : 0;
    const int e0i  = team * BT;
    const int bb0  = blockIdx.x * NE;

    __shared__ __align__(16) float whh_l[3][GHL][HH][4];   // 76800 B
    __shared__ __align__(16) float h_s[2][NE][HH];

    float whr[3][HREG];
    float bh[3];
    #pragma unroll
    for (int g3 = 0; g3 < 3; ++g3) {
        const int row = g3 * 100 + ii;
        #pragma unroll
        for (int k = 0; k < HREG; ++k)
            whr[g3][k] = Whh[(long)row * HH + k];
        bh[g3] = bhh[row];
    }
    for (int idx = tid; idx < 3 * GHL * HH * 4; idx += 256) {
        int c  = idx & 3;
        int r  = (idx >> 2) % HH;
        int gg = ((idx >> 2) / HH) % GHL;
        int g3 = idx / (4 * HH * GHL);
        whh_l[g3][gg][r][c] = Whh[(long)(g3 * 100 + r) * HH + (HREG + gg * 4 + c)];
    }
    for (int idx = tid; idx < NE * HH; idx += 256) {
        int e = idx / HH, k = idx % HH;
        h_s[0][e][k] = h_init ? h_init[(bb0 + e) * HH + k] : 0.f;
    }
    float gcur[3][BT];
    #pragma unroll
    for (int b = 0; b < BT; ++b) {
        const int e = e0i + b;
        const float* base;
        if constexpr (EMB) {
            base = table + (long)tgt[t0 * TB + bb0 + e] * 300;
        } else {
            base = gi + (long)(bb0 + e) * 300;
        }
        #pragma unroll
        for (int g3 = 0; g3 < 3; ++g3) gcur[g3][b] = base[g3 * 100 + ii];
    }
    __syncthreads();

    int cur = 0;
    for (int t = t0; t < t1; ++t) {
        const int nxt = cur ^ 1;

        float gnxt[3][BT] = {};
        if (t + 1 < t1) {
            #pragma unroll
            for (int b = 0; b < BT; ++b) {
                const int e = e0i + b;
                const float* base;
                if constexpr (EMB) {
                    base = table + (long)tgt[(t + 1) * TB + bb0 + e] * 300;
                } else {
                    base = gi + ((long)(t + 1 - t0) * TB + bb0 + e) * 300;
                }
                #pragma unroll
                for (int g3 = 0; g3 < 3; ++g3) gnxt[g3][b] = base[g3 * 100 + ii];
            }
        }

        float acc[3][BT];
        #pragma unroll
        for (int g3 = 0; g3 < 3; ++g3)
            #pragma unroll
            for (int b = 0; b < BT; ++b) acc[g3][b] = bh[g3];
        dot_reg<BT, HH, HREG>(std::make_index_sequence<GHR>{}, whr,
                              h_s[cur], e0i, acc);
        dot_lds3<GHR, BT, HH, GHL>(std::make_index_sequence<GHL>{}, whh_l, ii,
                                   h_s[cur], e0i, acc);

        #pragma unroll
        for (int b = 0; b < BT; ++b) {
            float r  = sigmoidf_(gcur[0][b] + acc[0][b]);
            float z  = sigmoidf_(gcur[1][b] + acc[1][b]);
            float n  = tanhf_(gcur[2][b] + r * acc[2][b]);
            float hp = h_s[cur][e0i + b][ii];
            float hn = (1.f - z) * n + z * hp;
            if (act) {
                h_s[nxt][e0i + b][li] = hn;
                if constexpr (WRITE_SEQ)
                    seq_out[((long)t * TB + bb0 + e0i + b) * HH + li] = hn;
            }
        }
        __syncthreads();
        #pragma unroll
        for (int g3 = 0; g3 < 3; ++g3)
            #pragma unroll
            for (int b = 0; b < BT; ++b) gcur[g3][b] = gnxt[g3][b];
        cur = nxt;
    }

    if (h_last != nullptr && act) {
        #pragma unroll
        for (int b = 0; b < BT; ++b)
            h_last[(bb0 + e0i + b) * HH + li] = h_s[cur][e0i + b][li];
    }
}

// ===========================================================================
// FALLBACK: R0's proven gru_kernel (verbatim) for encoders when ws has no
// room for gi chunks.
// ===========================================================================
template<int KK, int BT, int LD>
__device__ __forceinline__ void fma_step(const float* __restrict__ w,
                                         const float (*xs)[LD],
                                         float* __restrict__ acc) {
    #pragma unroll
    for (int b = 0; b < BT; ++b) {
        const float4 xv = *reinterpret_cast<const float4*>(&xs[b][KK]);
        acc[b] += w[KK]     * xv.x + w[KK + 1] * xv.y
                + w[KK + 2] * xv.z + w[KK + 3] * xv.w;
    }
}
template<int BT, int LD, size_t... Is>
__device__ __forceinline__ void gemv4(std::index_sequence<Is...>,
                                      const float* __restrict__ w,
                                      const float (*xs)[LD],
                                      float* __restrict__ acc) {
    (fma_step<(int)(Is * 4), BT, LD>(w, xs, acc), ...);
}
template<int GRP, int BT>
__device__ __forceinline__ void fma_lds_step(const float* __restrict__ wl,
                                             int row,
                                             const float (*hs)[HH],
                                             float* __restrict__ acc) {
    const float4 wv = *reinterpret_cast<const float4*>(wl + (GRP * GG + row) * 4);
    #pragma unroll
    for (int b = 0; b < BT; ++b) {
        const float4 hv = *reinterpret_cast<const float4*>(&hs[b][GRP * 4]);
        acc[b] += wv.x * hv.x + wv.y * hv.y + wv.z * hv.z + wv.w * hv.w;
    }
}
template<int BT, size_t... Is>
__device__ __forceinline__ void gemv_lds(std::index_sequence<Is...>,
                                         const float* __restrict__ wl, int row,
                                         const float (*hs)[HH],
                                         float* __restrict__ acc) {
    (fma_lds_step<(int)Is, BT>(wl, row, hs, acc), ...);
}

template<int K, bool EMB, bool WRITE_SEQ>
__global__ __launch_bounds__(640, 3)
void gru_old(const float* __restrict__ xin,
             const int*   __restrict__ tgt,
             const float* __restrict__ emb,
             const float* __restrict__ Wih,
             const float* __restrict__ Whh,
             const float* __restrict__ bih,
             const float* __restrict__ bhh,
             const float* __restrict__ h_init,
             float* __restrict__ seq_out,
             float* __restrict__ h_last,
             int T)
{
    constexpr int KP = (K + 3) & ~3;
    constexpr int BT = 2;
    constexpr int NT = 2;
    static_assert(KP % 4 == 0, "");

    const int tid  = threadIdx.x;
    const int team = tid / 320;
    const int tj   = tid % 320;
    const int bb0  = blockIdx.x * (BT * NT) + team * BT;
    const int g    = tj / 100;
    const int i    = tj % 100;

    __shared__ __align__(16) float whh_l[(HH / 4) * GG * 4];
    __shared__ __align__(16) float h_s[NT][BT][HH];
    __shared__ __align__(16) float x_s[NT][BT][KP];
    __shared__ float r_s[NT][BT][HH];
    __shared__ float z_s[NT][BT][HH];
    __shared__ float emb_s[EMB ? 64 : 1][EMB ? 28 : 4];
    __shared__ int   tgt_s[NT * BT];

    const int jj = (tj < GG) ? tj : 0;
    float wih[KP];
    ldN(std::make_index_sequence<K>{}, wih, Wih + (long)jj * K);
    #pragma unroll
    for (int k = K; k < KP; ++k) wih[k] = 0.f;
    float bi = bih[jj];
    float bh = bhh[jj];

    for (int idx = tid; idx < GG * HH; idx += 640) {
        int row = idx / HH, k = idx % HH;
        whh_l[((k >> 2) * GG + row) * 4 + (k & 3)] = Whh[row * HH + k];
    }
    for (int idx = tj; idx < BT * HH; idx += 320) {
        int b = idx / HH, k = idx % HH;
        h_s[team][b][k] = h_init ? h_init[(bb0 + b) * HH + k] : 0.f;
    }
    if constexpr (EMB) {
        for (int idx = tid; idx < 64 * 28; idx += 640) {
            int d = idx / 28, k = idx % 28;
            emb_s[d][k] = (k < 26) ? emb[d * 26 + k] : 0.f;
        }
        __syncthreads();
        for (int idx = tj; idx < BT * KP; idx += 320) {
            int b = idx / KP, k = idx % KP;
            int t0 = tgt[bb0 + b];
            x_s[team][b][k] = emb_s[t0][k];
        }
    } else {
        for (int idx = tj; idx < BT * KP; idx += 320) {
            int b = idx / KP, k = idx % KP;
            x_s[team][b][k] = (k < K) ? xin[(bb0 + b) * K + k] : 0.f;
        }
    }
    __syncthreads();

    for (int t = 0; t < T; ++t) {
        pinN(std::make_index_sequence<KP>{}, wih);
        bi = pin_val(bi);
        bh = pin_val(bh);

        const bool has_next = (t + 1 < T);
        float px = 0.f;
        int   ptg = 0;
        if constexpr (!EMB) {
            if (has_next && !(tj >= 200 && tj < 300)) {
                int stid = (tj < 200) ? tj : tj - 100;
                if (stid < BT * K)
                    px = xin[((t + 1) * TB + bb0 + stid / K) * K + stid % K];
            }
        } else {
            if (has_next && tj < BT) ptg = tgt[(t + 1) * TB + bb0 + tj];
        }

        float acc_i[BT], acc_h[BT];
        #pragma unroll
        for (int b = 0; b < BT; ++b) { acc_i[b] = bi; acc_h[b] = bh; }

        gemv4<BT, KP>(std::make_index_sequence<KP / 4>{}, wih, x_s[team], acc_i);
        gemv_lds<BT>(std::make_index_sequence<HH / 4>{}, whh_l, jj, h_s[team], acc_h);

        if (tj < 200) {
            #pragma unroll
            for (int b = 0; b < BT; ++b) {
                float v = sigmoidf_(acc_i[b] + acc_h[b]);
                if (g == 0) r_s[team][b][i] = v;
                else        z_s[team][b][i] = v;
            }
        }
        __syncthreads();

        if (tj >= 200 && tj < 300) {
            #pragma unroll
            for (int b = 0; b < BT; ++b) {
                float n  = tanhf_(acc_i[b] + r_s[team][b][i] * acc_h[b]);
                float z  = z_s[team][b][i];
                float hn = (1.f - z) * n + z * h_s[team][b][i];
                h_s[team][b][i] = hn;
                if (WRITE_SEQ)
                    seq_out[((long)t * TB + bb0 + b) * HH + i] = hn;
            }
        } else if constexpr (!EMB) {
            if (has_next) {
                int stid = (tj < 200) ? tj : tj - 100;
                if (stid < BT * K) x_s[team][stid / K][stid % K] = px;
            }
        }
        if constexpr (EMB) {
            if (has_next && tj < BT) tgt_s[team * BT + tj] = ptg;
            __syncthreads();
            if (has_next && tj < BT * KP) {
                int b = tj / KP, k = tj % KP;
                x_s[team][b][k] = emb_s[tgt_s[team * BT + b]][k];
            }
        }
        __syncthreads();
    }

    if (h_last != nullptr && tj >= 200 && tj < 300) {
        #pragma unroll
        for (int b = 0; b < BT; ++b)
            h_last[(bb0 + b) * HH + i] = h_s[team][b][i];
    }
}

// Final linear + argmax + target_cal.
__global__ __launch_bounds__(256)
void final_kernel(const float* __restrict__ d1,
                  const float* __restrict__ linW,   // [64,100]
                  const float* __restrict__ linb,   // [64]
                  const int*   __restrict__ tgt,    // [80,1024]
                  float* __restrict__ out0,         // [79*1024,64] logits
                  float* __restrict__ out1,         // [79*1024] target_cal
                  float* __restrict__ out2)         // [79*1024] argmax
{
    __shared__ float WT[HH][64];
    __shared__ __align__(16) float row[4][HH];

    const int tid = threadIdx.x;
    for (int idx = tid; idx < 64 * HH; idx += 256) {
        int d = idx / HH, k = idx % HH;
        WT[k][d] = linW[idx];
    }
    const int s    = tid >> 6;
    const int d    = tid & 63;
    const int slot = blockIdx.x * 4 + s;
    const int p    = slot >> 10;
    const int b    = slot & 1023;
    const float* drow = &d1[(long)(p * TB + b) * HH];
    __syncthreads();
    if (d < 50) {
        float2 v = *reinterpret_cast<const float2*>(&drow[2 * d]);
        row[s][2 * d]     = v.x;
        row[s][2 * d + 1] = v.y;
    }
    __syncthreads();

    float acc = linb[d];
    #pragma unroll
    for (int k = 0; k < HH; ++k)
        acc += row[s][k] * WT[k][d];

    out0[(long)slot * 64 + d] = acc;

    float mv = acc;
    int   mi = d;
    #pragma unroll
    for (int off = 32; off >= 1; off >>= 1) {
        float ov = __shfl_xor(mv, off, 64);
        int   oi = __shfl_xor(mi, off, 64);
        if (ov > mv || (ov == mv && oi < mi)) { mv = ov; mi = oi; }
    }
    if (d == 0) out2[slot] = (float)mi;
    if (d == 1) out1[slot] = (float)tgt[(p + 1) * TB + b];
}

extern "C" void kernel_launch(void* const* d_in, const int* in_sizes, int n_in,
                              void* d_out, int out_size, void* d_ws, size_t ws_size,
                              hipStream_t stream)
{
    const float* x      = (const float*)d_in[0];
    const int*   target = (const int*)  d_in[1];
    const float* emb    = (const float*)d_in[2];
    const float* eWih0  = (const float*)d_in[3];
    const float* eWhh0  = (const float*)d_in[4];
    const float* ebih0  = (const float*)d_in[5];
    const float* ebhh0  = (const float*)d_in[6];
    const float* eWih1  = (const float*)d_in[7];
    const float* eWhh1  = (const float*)d_in[8];
    const float* ebih1  = (const float*)d_in[9];
    const float* ebhh1  = (const float*)d_in[10];
    const float* dWih0  = (const float*)d_in[11];
    const float* dWhh0  = (const float*)d_in[12];
    const float* dbih0  = (const float*)d_in[13];
    const float* dbhh0  = (const float*)d_in[14];
    const float* dWih1  = (const float*)d_in[15];
    const float* dWhh1  = (const float*)d_in[16];
    const float* dbih1  = (const float*)d_in[17];
    const float* dbhh1  = (const float*)d_in[18];
    const float* linW   = (const float*)d_in[19];
    const float* linb   = (const float*)d_in[20];

    // workspace layout (floats): see R16 comment (unchanged).
    float* ws     = (float*)d_ws;
    float* h_enc0 = ws;
    float* h_enc1 = ws + 102400;
    float* e0     = ws + 204800;
    float* d0     = e0;
    float* d1_    = e0 + 8192000;
    float* gi_dec = e0 + 16384000;
    float* table  = e0 + 40960000;
    float* gi_enc = ws + 51404800;

    long ws_floats = (long)(ws_size / 4);
    long avail     = ws_floats - 51404800L;
    long Cmax      = (avail > 0) ? avail / 307200L : 0;
    int  C         = (int)((Cmax > 500) ? 500 : Cmax);
    const bool use_gi = (C >= 50);

    dim3 gG(512), gB(640);        // gemm_gi: 2 blocks/CU
    dim3 rG(256), rB(256);        // gru_rec

    if (use_gi) {
        for (int c0 = 0; c0 < 500; c0 += C) {
            int Cc = (500 - c0 < C) ? (500 - c0) : C;
            gemm_gi<26><<<gG, gB, 0, stream>>>(
                x + (long)c0 * TB * 26, eWih0, ebih0, gi_enc, Cc * TB);
            gru_rec<false, true><<<rG, rB, 0, stream>>>(
                gi_enc, nullptr, nullptr, eWhh0, ebhh0,
                c0 ? h_enc0 : nullptr, e0, h_enc0, c0, c0 + Cc);
        }
        for (int c0 = 0; c0 < 500; c0 += C) {
            int Cc = (500 - c0 < C) ? (500 - c0) : C;
            gemm_gi<100><<<gG, gB, 0, stream>>>(
                e0 + (long)c0 * TB * 100, eWih1, ebih1, gi_enc, Cc * TB);
            gru_rec<false, false><<<rG, rB, 0, stream>>>(
                gi_enc, nullptr, nullptr, eWhh1, ebhh1,
                c0 ? h_enc1 : nullptr, nullptr, h_enc1, c0, c0 + Cc);
        }
    } else {
        gru_old<26,  false, true ><<<dim3(256), dim3(640), 0, stream>>>(
            x, nullptr, nullptr, eWih0, eWhh0, ebih0, ebhh0, nullptr, e0, h_enc0, 500);
        gru_old<100, false, false><<<dim3(256), dim3(640), 0, stream>>>(
            e0, nullptr, nullptr, eWih1, eWhh1, ebih1, ebhh1, nullptr, nullptr, h_enc1, 500);
    }

    // decoder layer 0 (K=26, EMB): 64-row gi table, no gi buffer
    gemm_gi<26><<<gG, gB, 0, stream>>>(emb, dWih0, dbih0, table, 64);
    gru_rec<true, true><<<rG, rB, 0, stream>>>(
        nullptr, target, table, dWhh0, dbhh0, h_enc0, d0, nullptr, 0, 80);

    // decoder layer 1 (K=100): full gi fits inside dead e0 region
    gemm_gi<100><<<gG, gB, 0, stream>>>(d0, dWih1, dbih1, gi_dec, 80 * TB);
    gru_rec<false, true><<<rG, rB, 0, stream>>>(
        gi_dec, nullptr, nullptr, dWhh1, dbhh1, h_enc1, d1_, nullptr, 0, 80);

    float* out0 = (float*)d_out;
    float* out1 = out0 + (long)79 * 1024 * 64;
    float* out2 = out1 + 79 * 1024;
    final_kernel<<<dim3(20224), dim3(256), 0, stream>>>(d1_, linW, linb, target,
                                                        out0, out1, out2);
}